// Round 3
// baseline (261.138 us; speedup 1.0000x reference)
//
#include <hip/hip_runtime.h>

// Soft-label cross entropy, fused single pass + in-kernel final reduction:
//   loss = mean_i [ (m_i + log(sum_j exp(p_ij - m_i))) * (sum_j t_ij) - sum_j t_ij*p_ij ]
// One wave per row (C=1000 = 250 float4). Both p AND t rows are loaded into
// registers up-front (8 x 16B non-temporal loads in flight per wave) so the
// max-reduce latency and the t-load latency overlap. Last-arriving block
// (device-scope atomic counter, reset via hipMemsetAsync each call) reduces
// the per-block partials -- no second kernel dispatch.

typedef float f32x4 __attribute__((ext_vector_type(4)));

#define WAVES_PER_BLOCK 4
#define BLOCK_THREADS 256
#define NBLOCKS 2048

__global__ __launch_bounds__(BLOCK_THREADS, 8)   // keep VGPR<=64 -> 8 waves/SIMD
void ce_fused_kernel(const float* __restrict__ pred,
                     const float* __restrict__ targ,
                     float* __restrict__ partial,      // [gridDim.x]
                     unsigned int* __restrict__ counter,
                     float* __restrict__ out,
                     int nrows, int C, float inv_n) {
    const int lane = threadIdx.x & 63;
    const int wid  = threadIdx.x >> 6;
    const int waves_total = gridDim.x * WAVES_PER_BLOCK;
    const int wave_global = blockIdx.x * WAVES_PER_BLOCK + wid;
    const int C4 = C >> 2;   // 250

    float acc_lse = 0.0f;  // wave-uniform after reduces: sum of lse_row * st_row
    float acc_tp  = 0.0f;  // lane-local: sum of t*p, reduced once at the end

    for (int row = wave_global; row < nrows; row += waves_total) {
        const f32x4* __restrict__ p4 = (const f32x4*)(pred + (size_t)row * C);
        const f32x4* __restrict__ t4 = (const f32x4*)(targ + (size_t)row * C);

        // Issue ALL loads first (p then t): 8 x 16B in flight per wave.
        f32x4 pv[4], tv[4];
        #pragma unroll
        for (int it = 0; it < 4; ++it) {
            int idx = lane + it * 64;
            if (idx < C4) pv[it] = __builtin_nontemporal_load(p4 + idx);
        }
        #pragma unroll
        for (int it = 0; it < 4; ++it) {
            int idx = lane + it * 64;
            if (idx < C4) tv[it] = __builtin_nontemporal_load(t4 + idx);
        }

        // Lane-local then wave-wide max over p (t loads still in flight).
        float m = -3.0e38f;
        #pragma unroll
        for (int it = 0; it < 4; ++it) {
            int idx = lane + it * 64;
            if (idx < C4)
                m = fmaxf(m, fmaxf(fmaxf(pv[it][0], pv[it][1]),
                                   fmaxf(pv[it][2], pv[it][3])));
        }
        #pragma unroll
        for (int off = 32; off > 0; off >>= 1)
            m = fmaxf(m, __shfl_xor(m, off, 64));

        // Phase 2: all-register compute.
        float se = 0.0f, st = 0.0f;
        #pragma unroll
        for (int it = 0; it < 4; ++it) {
            int idx = lane + it * 64;
            if (idx < C4) {
                f32x4 t = tv[it];
                f32x4 p = pv[it];
                se += __expf(p[0] - m) + __expf(p[1] - m)
                    + __expf(p[2] - m) + __expf(p[3] - m);
                st += (t[0] + t[1]) + (t[2] + t[3]);
                acc_tp += t[0]*p[0] + t[1]*p[1] + t[2]*p[2] + t[3]*p[3];
            }
        }
        #pragma unroll
        for (int off = 32; off > 0; off >>= 1) {
            se += __shfl_xor(se, off, 64);
            st += __shfl_xor(st, off, 64);
        }
        acc_lse += (m + __logf(se)) * st;
    }

    // Deferred reduce of lane-local t*p accumulation.
    #pragma unroll
    for (int off = 32; off > 0; off >>= 1)
        acc_tp += __shfl_xor(acc_tp, off, 64);

    float wave_sum = acc_lse - acc_tp;

    __shared__ float wsum[WAVES_PER_BLOCK];
    __shared__ float red[BLOCK_THREADS];
    __shared__ int   is_last;
    if (lane == 0) wsum[wid] = wave_sum;
    __syncthreads();
    if (threadIdx.x == 0) {
        float s = wsum[0] + wsum[1] + wsum[2] + wsum[3];
        partial[blockIdx.x] = s;
        __threadfence();                       // release: partial visible device-wide
        unsigned int old = atomicAdd(counter, 1u);   // device scope by default (m20)
        is_last = (old == (unsigned int)(gridDim.x - 1)) ? 1 : 0;
    }
    __syncthreads();

    if (is_last) {
        __threadfence();                       // acquire
        volatile const float* pv_part = (volatile const float*)partial;
        float s = 0.0f;
        for (int i = threadIdx.x; i < (int)gridDim.x; i += BLOCK_THREADS)
            s += pv_part[i];
        red[threadIdx.x] = s;
        __syncthreads();
        #pragma unroll
        for (int stride = BLOCK_THREADS / 2; stride > 0; stride >>= 1) {
            if ((int)threadIdx.x < stride) red[threadIdx.x] += red[threadIdx.x + stride];
            __syncthreads();
        }
        if (threadIdx.x == 0) out[0] = red[0] * inv_n;
    }
}

extern "C" void kernel_launch(void* const* d_in, const int* in_sizes, int n_in,
                              void* d_out, int out_size, void* d_ws, size_t ws_size,
                              hipStream_t stream) {
    const float* pred = (const float*)d_in[0];
    const float* targ = (const float*)d_in[1];
    float* out = (float*)d_out;

    const int C = 1000;
    const int N = in_sizes[0] / C;   // 131072

    // d_ws layout: [0..15] counter (cacheline-isolated), [16..] partials
    unsigned int* counter = (unsigned int*)d_ws;
    float* partial = (float*)d_ws + 16;

    int nblocks = NBLOCKS;           // 2048 x 4 waves = 8192 waves = 16 rows/wave
    size_t need = (size_t)(16 + nblocks) * sizeof(float);
    if (need > ws_size)
        nblocks = (int)(ws_size / sizeof(float)) - 16;
    if (nblocks < 1) nblocks = 1;

    // Reset arrival counter every call (graph-capturable async memset).
    hipMemsetAsync(counter, 0, sizeof(unsigned int), stream);

    ce_fused_kernel<<<nblocks, BLOCK_THREADS, 0, stream>>>(
        pred, targ, partial, counter, out, N, C, 1.0f / (float)N);
}

// Round 4
// 182.304 us; speedup vs baseline: 1.4324x; 1.4324x over previous
//
#include <hip/hip_runtime.h>

// Soft-label cross entropy, fused single pass + in-kernel final reduction:
//   loss = mean_i [ (m_i + log(sum_j exp(p_ij - m_i))) * (sum_j t_ij) - sum_j t_ij*p_ij ]
// One wave per row (C=1000 = 250 float4). p row held in registers across the
// max->exp phases; t streamed in phase 2 (short live ranges -- round-3's
// up-front t loads spilled under the 64-VGPR cap). Last-arriving block
// reduces the per-block partials. Cross-block visibility uses agent-scope
// atomic store/load (write-through, cache-bypassing) + vmcnt(0) ordering
// instead of __threadfence(): on gfx950 the per-XCD L2s are non-coherent and
// a full device-scope fence (buffer_wbl2) per block is expensive; the only
// globally-visible write per block is partial[bid], so ordering just that
// store suffices.

typedef float f32x4 __attribute__((ext_vector_type(4)));

#define WAVES_PER_BLOCK 4
#define BLOCK_THREADS 256
#define NBLOCKS 2048

__global__ __launch_bounds__(BLOCK_THREADS, 8)   // keep VGPR<=64 -> 8 waves/SIMD
void ce_fused_kernel(const float* __restrict__ pred,
                     const float* __restrict__ targ,
                     float* __restrict__ partial,      // [gridDim.x]
                     unsigned int* __restrict__ counter,
                     float* __restrict__ out,
                     int nrows, int C, float inv_n) {
    const int lane = threadIdx.x & 63;
    const int wid  = threadIdx.x >> 6;
    const int waves_total = gridDim.x * WAVES_PER_BLOCK;
    const int wave_global = blockIdx.x * WAVES_PER_BLOCK + wid;
    const int C4 = C >> 2;   // 250

    float acc_lse = 0.0f;  // wave-uniform after reduces: sum of lse_row * st_row
    float acc_tp  = 0.0f;  // lane-local: sum of t*p, reduced once at the end

    for (int row = wave_global; row < nrows; row += waves_total) {
        const f32x4* __restrict__ p4 = (const f32x4*)(pred + (size_t)row * C);
        const f32x4* __restrict__ t4 = (const f32x4*)(targ + (size_t)row * C);

        // Phase 1: load p row into registers (non-temporal), wave max.
        f32x4 pv[4];
        float m = -3.0e38f;
        #pragma unroll
        for (int it = 0; it < 4; ++it) {
            int idx = lane + it * 64;
            if (idx < C4) pv[it] = __builtin_nontemporal_load(p4 + idx);
        }
        #pragma unroll
        for (int it = 0; it < 4; ++it) {
            int idx = lane + it * 64;
            if (idx < C4)
                m = fmaxf(m, fmaxf(fmaxf(pv[it][0], pv[it][1]),
                                   fmaxf(pv[it][2], pv[it][3])));
        }
        #pragma unroll
        for (int off = 32; off > 0; off >>= 1)
            m = fmaxf(m, __shfl_xor(m, off, 64));

        // Phase 2: stream t (short live ranges -- no spill), accumulate.
        float se = 0.0f, st = 0.0f;
        #pragma unroll
        for (int it = 0; it < 4; ++it) {
            int idx = lane + it * 64;
            if (idx < C4) {
                f32x4 t = __builtin_nontemporal_load(t4 + idx);
                f32x4 p = pv[it];
                se += __expf(p[0] - m) + __expf(p[1] - m)
                    + __expf(p[2] - m) + __expf(p[3] - m);
                st += (t[0] + t[1]) + (t[2] + t[3]);
                acc_tp += t[0]*p[0] + t[1]*p[1] + t[2]*p[2] + t[3]*p[3];
            }
        }
        #pragma unroll
        for (int off = 32; off > 0; off >>= 1) {
            se += __shfl_xor(se, off, 64);
            st += __shfl_xor(st, off, 64);
        }
        acc_lse += (m + __logf(se)) * st;
    }

    // Deferred reduce of lane-local t*p accumulation.
    #pragma unroll
    for (int off = 32; off > 0; off >>= 1)
        acc_tp += __shfl_xor(acc_tp, off, 64);

    float wave_sum = acc_lse - acc_tp;

    __shared__ float wsum[WAVES_PER_BLOCK];
    __shared__ float red[BLOCK_THREADS];
    __shared__ int   is_last;
    if (lane == 0) wsum[wid] = wave_sum;
    __syncthreads();
    if (threadIdx.x == 0) {
        float s = wsum[0] + wsum[1] + wsum[2] + wsum[3];
        // Agent-scope (device) write-through store: visible at the coherence
        // point, bypasses the non-coherent per-XCD L2 for readers.
        __hip_atomic_store(&partial[blockIdx.x], s,
                           __ATOMIC_RELAXED, __HIP_MEMORY_SCOPE_AGENT);
        // Ensure the store has completed device-wide before signalling.
        asm volatile("s_waitcnt vmcnt(0)" ::: "memory");
        unsigned int old = __hip_atomic_fetch_add(counter, 1u,
                           __ATOMIC_RELAXED, __HIP_MEMORY_SCOPE_AGENT);
        is_last = (old == (unsigned int)(gridDim.x - 1)) ? 1 : 0;
    }
    __syncthreads();

    if (is_last) {
        float s = 0.0f;
        for (int i = threadIdx.x; i < (int)gridDim.x; i += BLOCK_THREADS)
            s += __hip_atomic_load(&partial[i],
                                   __ATOMIC_RELAXED, __HIP_MEMORY_SCOPE_AGENT);
        red[threadIdx.x] = s;
        __syncthreads();
        #pragma unroll
        for (int stride = BLOCK_THREADS / 2; stride > 0; stride >>= 1) {
            if ((int)threadIdx.x < stride) red[threadIdx.x] += red[threadIdx.x + stride];
            __syncthreads();
        }
        if (threadIdx.x == 0) out[0] = red[0] * inv_n;
    }
}

extern "C" void kernel_launch(void* const* d_in, const int* in_sizes, int n_in,
                              void* d_out, int out_size, void* d_ws, size_t ws_size,
                              hipStream_t stream) {
    const float* pred = (const float*)d_in[0];
    const float* targ = (const float*)d_in[1];
    float* out = (float*)d_out;

    const int C = 1000;
    const int N = in_sizes[0] / C;   // 131072

    // d_ws layout: [0..15] counter (cacheline-isolated), [16..] partials
    unsigned int* counter = (unsigned int*)d_ws;
    float* partial = (float*)d_ws + 16;

    int nblocks = NBLOCKS;           // 2048 x 4 waves = 8192 waves = 16 rows/wave
    size_t need = (size_t)(16 + nblocks) * sizeof(float);
    if (need > ws_size)
        nblocks = (int)(ws_size / sizeof(float)) - 16;
    if (nblocks < 1) nblocks = 1;

    // Reset arrival counter every call (graph-capturable async memset node).
    hipMemsetAsync(counter, 0, sizeof(unsigned int), stream);

    ce_fused_kernel<<<nblocks, BLOCK_THREADS, 0, stream>>>(
        pred, targ, partial, counter, out, N, C, 1.0f / (float)N);
}